// Round 8
// baseline (19565.096 us; speedup 1.0000x reference)
//
#include <hip/hip_runtime.h>
#include <hip/hip_bf16.h>

// Problem constants
#define TT 128
#define BB 256
#define HH 2048
#define CC 64
#define EE 1024   // E = H // 2

typedef __bf16 bf16x8 __attribute__((ext_vector_type(8)));
typedef float  f32x4  __attribute__((ext_vector_type(4)));

__device__ __forceinline__ ushort f2b(float f) {
    unsigned u = __builtin_bit_cast(unsigned, f);
    u += 0x7fffu + ((u >> 16) & 1u);          // round-to-nearest-even
    return (ushort)(u >> 16);
}
__device__ __forceinline__ float b2f(ushort u) {
    return __builtin_bit_cast(float, (unsigned)u << 16);
}

// ---------------------------------------------------------------------------
// Pack W_*h -> SINGLE-plane bf16, gate-interleaved rows m = 4*j + gate.
// (Round-7 evidence: split precision unnecessary; amplification < 4.)
// ---------------------------------------------------------------------------
__global__ __launch_bounds__(256) void pack_wh(
    const float* __restrict__ Wg, const float* __restrict__ Wi,
    const float* __restrict__ Wf, const float* __restrict__ Wo,
    ushort* __restrict__ Wp)
{
    unsigned idx = blockIdx.x * 256u + threadIdx.x;   // one per 4 elems; grid 16384
    unsigned kg = idx & 511u;                         // k/4 (2048/4)
    unsigned m  = idx >> 9;                           // 0..8191
    unsigned gate = m & 3u, j = m >> 2;
    const float* W = (gate == 0) ? Wg : (gate == 1) ? Wi : (gate == 2) ? Wf : Wo;
    float4 v = reinterpret_cast<const float4*>(W + (size_t)j * HH)[kg];
    ushort4 o;
    o.x = f2b(v.x); o.y = f2b(v.y); o.z = f2b(v.z); o.w = f2b(v.w);
    reinterpret_cast<ushort4*>(Wp)[idx] = o;
}

// ---------------------------------------------------------------------------
// Pack W_*x [2048][1024] -> hi/lo bf16, gate-interleaved [8192][1024].
// ---------------------------------------------------------------------------
__global__ __launch_bounds__(256) void pack_wx(
    const float* __restrict__ Wg, const float* __restrict__ Wi,
    const float* __restrict__ Wf, const float* __restrict__ Wo,
    ushort* __restrict__ Xhi, ushort* __restrict__ Xlo)
{
    unsigned idx = blockIdx.x * 256u + threadIdx.x;   // one per 4 elems; grid 8192
    unsigned kg = idx & 255u;                         // k/4 (1024/4)
    unsigned m  = idx >> 8;                           // 0..8191
    unsigned gate = m & 3u, j = m >> 2;
    const float* W = (gate == 0) ? Wg : (gate == 1) ? Wi : (gate == 2) ? Wf : Wo;
    float4 v = reinterpret_cast<const float4*>(W + (size_t)j * EE)[kg];
    ushort4 hi, lo;
    hi.x = f2b(v.x); lo.x = f2b(v.x - b2f(hi.x));
    hi.y = f2b(v.y); lo.y = f2b(v.y - b2f(hi.y));
    hi.z = f2b(v.z); lo.z = f2b(v.z - b2f(hi.z));
    hi.w = f2b(v.w); lo.w = f2b(v.w - b2f(hi.w));
    reinterpret_cast<ushort4*>(Xhi)[idx] = hi;
    reinterpret_cast<ushort4*>(Xlo)[idx] = lo;
}

// ---------------------------------------------------------------------------
// Pack embedding [64][1024] -> hi/lo bf16.
// ---------------------------------------------------------------------------
__global__ __launch_bounds__(256) void pack_emb(
    const float* __restrict__ emb, ushort* __restrict__ Ehi, ushort* __restrict__ Elo)
{
    unsigned idx = blockIdx.x * 256u + threadIdx.x;   // one per 4 elems; grid 64
    float4 v = reinterpret_cast<const float4*>(emb)[idx];
    ushort4 hi, lo;
    hi.x = f2b(v.x); lo.x = f2b(v.x - b2f(hi.x));
    hi.y = f2b(v.y); lo.y = f2b(v.y - b2f(hi.y));
    hi.z = f2b(v.z); lo.z = f2b(v.z - b2f(hi.z));
    hi.w = f2b(v.w); lo.w = f2b(v.w - b2f(hi.w));
    reinterpret_cast<ushort4*>(Ehi)[idx] = hi;
    reinterpret_cast<ushort4*>(Elo)[idx] = lo;
}

// ---------------------------------------------------------------------------
// xproj GEMM: xproj[c][m] = (Wx @ emb^T)[m][c] + b_gate[j],  K = 1024.
// Split-precision (3 products) = fp32-grade. Reads W_x ONCE (round 7 read it
// 64x with scalar loads -> 1306 us; this is ~15 us).
// Grid 128 blocks x 256 thr (4 waves: 2m x 2n), block tile 64(M) x 64(N=C).
// ---------------------------------------------------------------------------
__global__ __launch_bounds__(256) void xproj_gemm(
    const ushort* __restrict__ Xhi, const ushort* __restrict__ Xlo,
    const ushort* __restrict__ Ehi, const ushort* __restrict__ Elo,
    const float*  __restrict__ bg,  const float*  __restrict__ bi,
    const float*  __restrict__ bf_, const float*  __restrict__ bo,
    float* __restrict__ xproj)
{
    const int l   = threadIdx.x & 63;
    const int wid = threadIdx.x >> 6;            // 0..3
    const int q   = l >> 4;
    const int r15 = l & 15;
    const int m0  = blockIdx.x * 64 + (wid >> 1) * 32;
    const int n0  = (wid & 1) * 32;

    f32x4 acc[2][2] = {};
    const size_t aoff = (size_t)(m0 + r15) * EE + 8 * q;
    const size_t boff = (size_t)(n0 + r15) * EE + 8 * q;

    for (int k0 = 0; k0 < EE; k0 += 32) {
        bf16x8 ah[2], al[2], bh[2], bl[2];
        #pragma unroll
        for (int mt = 0; mt < 2; ++mt) {
            ah[mt] = *reinterpret_cast<const bf16x8*>(Xhi + aoff + (size_t)mt * 16 * EE + k0);
            al[mt] = *reinterpret_cast<const bf16x8*>(Xlo + aoff + (size_t)mt * 16 * EE + k0);
        }
        #pragma unroll
        for (int nt = 0; nt < 2; ++nt) {
            bh[nt] = *reinterpret_cast<const bf16x8*>(Ehi + boff + (size_t)nt * 16 * EE + k0);
            bl[nt] = *reinterpret_cast<const bf16x8*>(Elo + boff + (size_t)nt * 16 * EE + k0);
        }
        #pragma unroll
        for (int mt = 0; mt < 2; ++mt)
            #pragma unroll
            for (int nt = 0; nt < 2; ++nt) {
                acc[mt][nt] = __builtin_amdgcn_mfma_f32_16x16x32_bf16(ah[mt], bh[nt], acc[mt][nt], 0, 0, 0);
                acc[mt][nt] = __builtin_amdgcn_mfma_f32_16x16x32_bf16(ah[mt], bl[nt], acc[mt][nt], 0, 0, 0);
                acc[mt][nt] = __builtin_amdgcn_mfma_f32_16x16x32_bf16(al[mt], bh[nt], acc[mt][nt], 0, 0, 0);
            }
    }

    // acc[mt][nt][r] = out[m0+mt*16+4q+r][n0+nt*16+r15]; m=4j+gate, gate=r.
    #pragma unroll
    for (int nt = 0; nt < 2; ++nt) {
        int c = n0 + nt * 16 + r15;            // class/embedding row
        #pragma unroll
        for (int mt = 0; mt < 2; ++mt) {
            int j = (m0 >> 2) + mt * 4 + q;    // hidden unit
            float4 o;
            o.x = acc[mt][nt][0] + bg[j];
            o.y = acc[mt][nt][1] + bi[j];
            o.z = acc[mt][nt][2] + bf_[j];
            o.w = acc[mt][nt][3] + bo[j];
            reinterpret_cast<float4*>(xproj + (size_t)c * (4 * HH))[j] = o;
        }
    }
}

// ---------------------------------------------------------------------------
// Zero h0 (bf16 [B][H]) and the grid-barrier counter. (ws is poisoned 0xAA.)
// ---------------------------------------------------------------------------
__global__ __launch_bounds__(256) void zinit(unsigned* __restrict__ h0,
                                             unsigned* __restrict__ bar)
{
    unsigned i = blockIdx.x * 256u + threadIdx.x;     // grid 1024 -> 262144 dwords
    h0[i] = 0u;
    if (i == 0) bar[0] = 0u;
}

// ---------------------------------------------------------------------------
// Persistent LSTM: ONE kernel runs all 128 timesteps; grid barrier between.
// 256 blocks x 512 thr (co-resident by capacity: 256 blocks <= 256 CUs, and
// even pathological placement fits since each CU holds up to 4 such blocks).
// Block tile 64(M)x128(N), wave 32x32, single-plane bf16 MFMA, cell state in
// REGISTERS (each thread owns its (j,n) cells across all steps).
// Cross-XCD h visibility: __threadfence (agent scope: L2 wb/inv) + monotonic
// atomic counter barrier.
// ---------------------------------------------------------------------------
__global__ __launch_bounds__(512, 1) void lstm_persist(
    const ushort* __restrict__ Wp,     // [8192][2048] bf16 gate-interleaved
    const float*  __restrict__ xproj,  // [64][8192] fp32
    const int*    __restrict__ x,      // [256][128] int32
    ushort*       __restrict__ h0,     // [256][2048] bf16 (transposed h)
    ushort*       __restrict__ h1,
    unsigned*     __restrict__ bar)
{
    const int l   = threadIdx.x & 63;
    const int wid = threadIdx.x >> 6;            // 0..7
    const int q   = l >> 4;
    const int r15 = l & 15;
    const int bm  = blockIdx.x >> 1;             // 0..127
    const int bn  = blockIdx.x & 1;
    const int m0  = bm * 64 + (wid >> 2) * 32;
    const int n0  = bn * 128 + (wid & 3) * 32;

    const size_t aoff = (size_t)(m0 + r15) * HH + 8 * q;
    const size_t boff = (size_t)(n0 + r15) * HH + 8 * q;

    float creg[2][2] = {{0.f, 0.f}, {0.f, 0.f}};   // cell state, in registers

    for (int t = 0; t < TT; ++t) {
        const ushort* hp = (t & 1) ? h1 : h0;
        ushort*       hn = (t & 1) ? h0 : h1;

        f32x4 acc[2][2] = {};
        #pragma unroll 2
        for (int k0 = 0; k0 < HH; k0 += 32) {
            bf16x8 a[2], b[2];
            #pragma unroll
            for (int mt = 0; mt < 2; ++mt)
                a[mt] = *reinterpret_cast<const bf16x8*>(Wp + aoff + (size_t)mt * 16 * HH + k0);
            #pragma unroll
            for (int nt = 0; nt < 2; ++nt)
                b[nt] = *reinterpret_cast<const bf16x8*>(hp + boff + (size_t)nt * 16 * HH + k0);
            #pragma unroll
            for (int mt = 0; mt < 2; ++mt)
                #pragma unroll
                for (int nt = 0; nt < 2; ++nt)
                    acc[mt][nt] = __builtin_amdgcn_mfma_f32_16x16x32_bf16(
                        a[mt], b[nt], acc[mt][nt], 0, 0, 0);
        }

        // Epilogue: gate = acc reg index r (rows gate-interleaved).
        #pragma unroll
        for (int nt = 0; nt < 2; ++nt) {
            int n = n0 + nt * 16 + r15;
            int cidx = x[n * TT + t];
            const float4* xp4 = reinterpret_cast<const float4*>(xproj + (size_t)cidx * (4 * HH));
            #pragma unroll
            for (int mt = 0; mt < 2; ++mt) {
                int j = (m0 >> 2) + mt * 4 + q;
                float4 xp = xp4[j];
                float pg = acc[mt][nt][0] + xp.x;
                float pi = acc[mt][nt][1] + xp.y;
                float pf = acc[mt][nt][2] + xp.z;
                float po = acc[mt][nt][3] + xp.w;
                float g  = tanhf(pg);
                float ii = 1.0f / (1.0f + expf(-pi));
                float ff = 1.0f / (1.0f + expf(-pf));
                float oo = 1.0f / (1.0f + expf(-po));
                float cn = g * ii + creg[mt][nt] * ff;
                creg[mt][nt] = cn;
                hn[(size_t)n * HH + j] = f2b(tanhf(cn) * oo);
            }
        }

        // -------- grid barrier (monotonic counter; no reset races) --------
        __threadfence();                 // release: my h writes -> device scope
        __syncthreads();                 // whole block has fenced
        if (threadIdx.x == 0) {
            atomicAdd(bar, 1u);
            unsigned target = 256u * (unsigned)(t + 1);
            while (atomicAdd(bar, 0u) < target) __builtin_amdgcn_s_sleep(2);
        }
        __syncthreads();
        __threadfence();                 // acquire: invalidate stale caches
    }
}

// ---------------------------------------------------------------------------
// final: p = W_ph @ h + b_p ; out[b][c] = log_softmax over c.
// ---------------------------------------------------------------------------
__global__ __launch_bounds__(256) void final_proj(
    const ushort* __restrict__ hT,     // [256][2048] bf16
    const float*  __restrict__ Wph,    // [64][2048] fp32
    const float*  __restrict__ bp,     // [64]
    float*        __restrict__ out)    // [256][64]
{
    __shared__ float part[256];
    int b  = blockIdx.x;
    int c  = threadIdx.x & 63;
    int sl = threadIdx.x >> 6;         // 0..3
    const ushort* hrow = hT  + (size_t)b * HH + sl * 512;
    const float*  wrow = Wph + (size_t)c * HH + sl * 512;
    float s = 0.0f;
    #pragma unroll 8
    for (int k = 0; k < 512; ++k) s += wrow[k] * b2f(hrow[k]);
    part[threadIdx.x] = s;
    __syncthreads();
    if (threadIdx.x < 64) {
        float p = part[c] + part[64 + c] + part[128 + c] + part[192 + c] + bp[c];
        float mx = p;
        #pragma unroll
        for (int off = 32; off > 0; off >>= 1) mx = fmaxf(mx, __shfl_xor(mx, off));
        float ex = expf(p - mx), sum = ex;
        #pragma unroll
        for (int off = 32; off > 0; off >>= 1) sum += __shfl_xor(sum, off);
        out[(size_t)b * CC + c] = p - mx - logf(sum);
    }
}

// ---------------------------------------------------------------------------
extern "C" void kernel_launch(void* const* d_in, const int* in_sizes, int n_in,
                              void* d_out, int out_size, void* d_ws, size_t ws_size,
                              hipStream_t stream)
{
    const int*   x    = (const int*)  d_in[0];
    const float* emb  = (const float*)d_in[1];   // [64][1024]
    const float* Wgx  = (const float*)d_in[2];   // [2048][1024]
    const float* Wix  = (const float*)d_in[3];
    const float* Wfx  = (const float*)d_in[4];
    const float* Wox  = (const float*)d_in[5];
    const float* Wgh  = (const float*)d_in[6];   // [2048][2048]
    const float* Wih  = (const float*)d_in[7];
    const float* Wfh  = (const float*)d_in[8];
    const float* Woh  = (const float*)d_in[9];
    const float* bg   = (const float*)d_in[10];
    const float* bi   = (const float*)d_in[11];
    const float* bf_  = (const float*)d_in[12];
    const float* bo   = (const float*)d_in[13];
    const float* Wph  = (const float*)d_in[14];  // [64][2048]
    const float* bp   = (const float*)d_in[15];

    char* ws = (char*)d_ws;
    const size_t MB = 1048576;
    ushort*   Wp    = (ushort*)(ws);                    // 32 MB
    ushort*   Xhi   = (ushort*)(ws + 32 * MB);          // 16 MB
    ushort*   Xlo   = (ushort*)(ws + 48 * MB);          // 16 MB
    ushort*   Ehi   = (ushort*)(ws + 64 * MB);          // 128 KB
    ushort*   Elo   = (ushort*)(ws + 64 * MB + 131072); // 128 KB
    float*    xproj = (float*) (ws + 65 * MB);          //  2 MB
    ushort*   h0    = (ushort*)(ws + 67 * MB);          //  1 MB
    ushort*   h1    = (ushort*)(ws + 68 * MB);          //  1 MB
    unsigned* bar   = (unsigned*)(ws + 69 * MB);        //  4 B  (end ~69 MB)

    pack_wh   <<<16384, 256, 0, stream>>>(Wgh, Wih, Wfh, Woh, Wp);
    pack_wx   <<<8192,  256, 0, stream>>>(Wgx, Wix, Wfx, Wox, Xhi, Xlo);
    pack_emb  <<<64,    256, 0, stream>>>(emb, Ehi, Elo);
    xproj_gemm<<<128,   256, 0, stream>>>(Xhi, Xlo, Ehi, Elo, bg, bi, bf_, bo, xproj);
    zinit     <<<1024,  256, 0, stream>>>((unsigned*)h0, bar);

    lstm_persist<<<256, 512, 0, stream>>>(Wp, xproj, x, h0, h1, bar);

    // T=128 even: final h in h0
    final_proj<<<BB, 256, 0, stream>>>(h0, Wph, bp, (float*)d_out);
}

// Round 9
// 11894.914 us; speedup vs baseline: 1.6448x; 1.6448x over previous
//
#include <hip/hip_runtime.h>
#include <hip/hip_bf16.h>

// Problem constants
#define TT 128
#define BB 256
#define HH 2048
#define CC 64
#define EE 1024   // E = H // 2

typedef __bf16 bf16x8 __attribute__((ext_vector_type(8)));
typedef float  f32x4  __attribute__((ext_vector_type(4)));
typedef unsigned long long u64;

__device__ __forceinline__ ushort f2b(float f) {
    unsigned u = __builtin_bit_cast(unsigned, f);
    u += 0x7fffu + ((u >> 16) & 1u);          // round-to-nearest-even
    return (ushort)(u >> 16);
}
__device__ __forceinline__ float b2f(ushort u) {
    return __builtin_bit_cast(float, (unsigned)u << 16);
}
// Agent-scope (device) relaxed atomics: write-through stores / L2-bypass loads.
// These give cross-XCD h coherence WITHOUT buffer_inv/wbl2 fences, so Wp stays
// hot in each XCD's L2 (round-8 lesson: __threadfence invalidated 32MB/step).
__device__ __forceinline__ u64 ld_agent(const u64* p) {
    return __hip_atomic_load(p, __ATOMIC_RELAXED, __HIP_MEMORY_SCOPE_AGENT);
}
__device__ __forceinline__ void st_agent(u64* p, u64 v) {
    __hip_atomic_store(p, v, __ATOMIC_RELAXED, __HIP_MEMORY_SCOPE_AGENT);
}

// ---------------------------------------------------------------------------
// prep (fused): pack W_*h -> bf16 gate-interleaved [8192][2048];
//               pack W_*x -> hi/lo bf16 gate-interleaved [8192][1024];
//               pack emb  -> hi/lo bf16 [64][1024].
// Grid 24640 x 256.
// ---------------------------------------------------------------------------
__global__ __launch_bounds__(256) void prep(
    const float* __restrict__ Wgh, const float* __restrict__ Wih,
    const float* __restrict__ Wfh, const float* __restrict__ Woh,
    const float* __restrict__ Wgx, const float* __restrict__ Wix,
    const float* __restrict__ Wfx, const float* __restrict__ Wox,
    const float* __restrict__ emb,
    ushort* __restrict__ Wp, ushort* __restrict__ Xhi, ushort* __restrict__ Xlo,
    ushort* __restrict__ Ehi, ushort* __restrict__ Elo)
{
    unsigned bid = blockIdx.x;
    if (bid < 16384u) {                                   // W_*h single-plane
        unsigned idx = bid * 256u + threadIdx.x;
        unsigned kg = idx & 511u, m = idx >> 9;
        unsigned gate = m & 3u, j = m >> 2;
        const float* W = (gate == 0) ? Wgh : (gate == 1) ? Wih : (gate == 2) ? Wfh : Woh;
        float4 v = reinterpret_cast<const float4*>(W + (size_t)j * HH)[kg];
        ushort4 o;
        o.x = f2b(v.x); o.y = f2b(v.y); o.z = f2b(v.z); o.w = f2b(v.w);
        reinterpret_cast<ushort4*>(Wp)[idx] = o;
    } else if (bid < 24576u) {                            // W_*x hi/lo
        unsigned idx = (bid - 16384u) * 256u + threadIdx.x;
        unsigned kg = idx & 255u, m = idx >> 8;
        unsigned gate = m & 3u, j = m >> 2;
        const float* W = (gate == 0) ? Wgx : (gate == 1) ? Wix : (gate == 2) ? Wfx : Wox;
        float4 v = reinterpret_cast<const float4*>(W + (size_t)j * EE)[kg];
        ushort4 hi, lo;
        hi.x = f2b(v.x); lo.x = f2b(v.x - b2f(hi.x));
        hi.y = f2b(v.y); lo.y = f2b(v.y - b2f(hi.y));
        hi.z = f2b(v.z); lo.z = f2b(v.z - b2f(hi.z));
        hi.w = f2b(v.w); lo.w = f2b(v.w - b2f(hi.w));
        reinterpret_cast<ushort4*>(Xhi)[idx] = hi;
        reinterpret_cast<ushort4*>(Xlo)[idx] = lo;
    } else {                                              // emb hi/lo
        unsigned idx = (bid - 24576u) * 256u + threadIdx.x;
        float4 v = reinterpret_cast<const float4*>(emb)[idx];
        ushort4 hi, lo;
        hi.x = f2b(v.x); lo.x = f2b(v.x - b2f(hi.x));
        hi.y = f2b(v.y); lo.y = f2b(v.y - b2f(hi.y));
        hi.z = f2b(v.z); lo.z = f2b(v.z - b2f(hi.z));
        hi.w = f2b(v.w); lo.w = f2b(v.w - b2f(hi.w));
        reinterpret_cast<ushort4*>(Ehi)[idx] = hi;
        reinterpret_cast<ushort4*>(Elo)[idx] = lo;
    }
}

// ---------------------------------------------------------------------------
// xz (fused): bid<128 -> xproj GEMM (split-precision, K=1024, fp32-grade);
//             else    -> zero h0 + barrier counter.
// Grid 1152 x 256.
// ---------------------------------------------------------------------------
__global__ __launch_bounds__(256) void xz(
    const ushort* __restrict__ Xhi, const ushort* __restrict__ Xlo,
    const ushort* __restrict__ Ehi, const ushort* __restrict__ Elo,
    const float*  __restrict__ bg,  const float*  __restrict__ bi,
    const float*  __restrict__ bf_, const float*  __restrict__ bo,
    float* __restrict__ xproj, unsigned* __restrict__ h0, unsigned* __restrict__ bar)
{
    unsigned bid = blockIdx.x;
    if (bid >= 128u) {                                    // init branch
        unsigned i = (bid - 128u) * 256u + threadIdx.x;   // 262144 dwords = 1MB
        h0[i] = 0u;
        if (i == 0) bar[0] = 0u;
        return;
    }
    const int l   = threadIdx.x & 63;
    const int wid = threadIdx.x >> 6;
    const int q   = l >> 4;
    const int r15 = l & 15;
    const int m0  = bid * 64 + (wid >> 1) * 32;
    const int n0  = (wid & 1) * 32;

    f32x4 acc[2][2] = {};
    const size_t aoff = (size_t)(m0 + r15) * EE + 8 * q;
    const size_t boff = (size_t)(n0 + r15) * EE + 8 * q;

    for (int k0 = 0; k0 < EE; k0 += 32) {
        bf16x8 ah[2], al[2], bh[2], bl[2];
        #pragma unroll
        for (int mt = 0; mt < 2; ++mt) {
            ah[mt] = *reinterpret_cast<const bf16x8*>(Xhi + aoff + (size_t)mt * 16 * EE + k0);
            al[mt] = *reinterpret_cast<const bf16x8*>(Xlo + aoff + (size_t)mt * 16 * EE + k0);
        }
        #pragma unroll
        for (int nt = 0; nt < 2; ++nt) {
            bh[nt] = *reinterpret_cast<const bf16x8*>(Ehi + boff + (size_t)nt * 16 * EE + k0);
            bl[nt] = *reinterpret_cast<const bf16x8*>(Elo + boff + (size_t)nt * 16 * EE + k0);
        }
        #pragma unroll
        for (int mt = 0; mt < 2; ++mt)
            #pragma unroll
            for (int nt = 0; nt < 2; ++nt) {
                acc[mt][nt] = __builtin_amdgcn_mfma_f32_16x16x32_bf16(ah[mt], bh[nt], acc[mt][nt], 0, 0, 0);
                acc[mt][nt] = __builtin_amdgcn_mfma_f32_16x16x32_bf16(ah[mt], bl[nt], acc[mt][nt], 0, 0, 0);
                acc[mt][nt] = __builtin_amdgcn_mfma_f32_16x16x32_bf16(al[mt], bh[nt], acc[mt][nt], 0, 0, 0);
            }
    }
    #pragma unroll
    for (int nt = 0; nt < 2; ++nt) {
        int c = n0 + nt * 16 + r15;
        #pragma unroll
        for (int mt = 0; mt < 2; ++mt) {
            int j = (m0 >> 2) + mt * 4 + q;
            float4 o;
            o.x = acc[mt][nt][0] + bg[j];
            o.y = acc[mt][nt][1] + bi[j];
            o.z = acc[mt][nt][2] + bf_[j];
            o.w = acc[mt][nt][3] + bo[j];
            reinterpret_cast<float4*>(xproj + (size_t)c * (4 * HH))[j] = o;
        }
    }
}

// ---------------------------------------------------------------------------
// Persistent LSTM + fused final projection. 256 blocks x 512 threads.
// - XCD-chunk swizzle: each XCD's 32 blocks hold a contiguous 4MB Wp slice
//   -> Wp L2-resident for all 128 steps (performance-only assumption).
// - h exchange: write-through agent stores (LDS-coalesced 8B) / L2-bypass
//   agent loads. NO fences anywhere -> L2 (weights) never invalidated.
// - Grid barrier: relaxed fetch_add + relaxed load poll, monotonic target.
// - Cell state in registers. Tail: W_ph @ h + log_softmax, block = batch b.
// ---------------------------------------------------------------------------
__global__ __launch_bounds__(512, 1) void lstm_persist(
    const ushort* __restrict__ Wp,     // [8192][2048] bf16 gate-interleaved
    const float*  __restrict__ xproj,  // [64][8192] fp32
    const int*    __restrict__ x,      // [256][128] int32
    ushort*       __restrict__ h0,     // [256][2048] bf16 (transposed h)
    ushort*       __restrict__ h1,
    unsigned*     __restrict__ bar,
    const float*  __restrict__ Wph,    // [64][2048] fp32
    const float*  __restrict__ bp,     // [64]
    float*        __restrict__ out)    // [256][64]
{
    __shared__ __align__(16) ushort sh[128 * 16];   // h-store staging (4KB)
    __shared__ float part[512];                     // tail reduction (2KB)

    const int tid = threadIdx.x;
    const int l   = tid & 63;
    const int wid = tid >> 6;                       // 0..7
    const int q   = l >> 4;
    const int r15 = l & 15;
    const int lg  = (blockIdx.x & 7) * 32 + (blockIdx.x >> 3);  // XCD chunk swizzle
    const int bm  = lg >> 1;                        // 0..127
    const int bn  = lg & 1;
    const int m0  = bm * 64 + (wid >> 2) * 32;
    const int n0  = bn * 128 + (wid & 3) * 32;

    const size_t aoff = (size_t)(m0 + r15) * HH + 8 * q;
    const size_t boff = (size_t)(n0 + r15) * HH + 8 * q;
    const int jb = (m0 >> 2);                       // wave j base

    float creg[2][2] = {{0.f, 0.f}, {0.f, 0.f}};    // cell state in registers

    for (int t = 0; t < TT; ++t) {
        const ushort* hp = (t & 1) ? h1 : h0;
        ushort*       hn = (t & 1) ? h0 : h1;

        f32x4 acc[2][2] = {};
        #pragma unroll 2
        for (int k0 = 0; k0 < HH; k0 += 32) {
            bf16x8 a[2];
            union { u64 u[2]; bf16x8 v; } b[2];
            #pragma unroll
            for (int mt = 0; mt < 2; ++mt)
                a[mt] = *reinterpret_cast<const bf16x8*>(Wp + aoff + (size_t)mt * 16 * HH + k0);
            #pragma unroll
            for (int nt = 0; nt < 2; ++nt) {
                const u64* p = reinterpret_cast<const u64*>(hp + boff + (size_t)nt * 16 * HH + k0);
                b[nt].u[0] = ld_agent(p);
                b[nt].u[1] = ld_agent(p + 1);
            }
            #pragma unroll
            for (int mt = 0; mt < 2; ++mt)
                #pragma unroll
                for (int nt = 0; nt < 2; ++nt)
                    acc[mt][nt] = __builtin_amdgcn_mfma_f32_16x16x32_bf16(
                        a[mt], b[nt].v, acc[mt][nt], 0, 0, 0);
        }

        // Epilogue: gate = acc reg index (rows gate-interleaved); h' -> LDS.
        #pragma unroll
        for (int nt = 0; nt < 2; ++nt) {
            int n = n0 + nt * 16 + r15;
            int cidx = x[n * TT + t];
            const float4* xp4 = reinterpret_cast<const float4*>(xproj + (size_t)cidx * (4 * HH));
            #pragma unroll
            for (int mt = 0; mt < 2; ++mt) {
                int j = jb + mt * 4 + q;
                float4 xp = xp4[j];
                float pg = acc[mt][nt][0] + xp.x;
                float pi = acc[mt][nt][1] + xp.y;
                float pf = acc[mt][nt][2] + xp.z;
                float po = acc[mt][nt][3] + xp.w;
                float g  = tanhf(pg);
                float ii = 1.0f / (1.0f + expf(-pi));
                float ff = 1.0f / (1.0f + expf(-pf));
                float oo = 1.0f / (1.0f + expf(-po));
                float cn = g * ii + creg[mt][nt] * ff;
                creg[mt][nt] = cn;
                int nloc = (wid & 3) * 32 + nt * 16 + r15;
                int jloc = (wid >> 2) * 8 + mt * 4 + q;
                sh[nloc * 16 + jloc] = f2b(tanhf(cn) * oo);
            }
        }
        __syncthreads();                            // sh complete
        {   // coalesced write-through flush: 512 x 8B
            int row = tid >> 2, c8 = tid & 3;
            u64 v = reinterpret_cast<const u64*>(sh)[tid];
            st_agent(reinterpret_cast<u64*>(hn + (size_t)(bn * 128 + row) * HH + bm * 16 + c8 * 4), v);
        }
        asm volatile("s_waitcnt vmcnt(0)" ::: "memory");
        __syncthreads();                            // all stores globally visible
        if (tid == 0) {
            __hip_atomic_fetch_add(bar, 1u, __ATOMIC_RELAXED, __HIP_MEMORY_SCOPE_AGENT);
            unsigned tgt = 256u * (unsigned)(t + 1);
            while (__hip_atomic_load(bar, __ATOMIC_RELAXED, __HIP_MEMORY_SCOPE_AGENT) < tgt)
                __builtin_amdgcn_s_sleep(4);
        }
        __syncthreads();                            // release whole block
    }

    // ---- fused final projection: p = W_ph @ h + b_p ; log_softmax over c ----
    // T=128 even -> final h in h0. Block = batch element (raw blockIdx).
    {
        int b  = blockIdx.x;
        int c  = tid & 63;
        int sl = tid >> 6;                          // 0..7, k-slice of 256
        const u64*   hrow = reinterpret_cast<const u64*>(h0 + (size_t)b * HH + sl * 256);
        const float* wrow = Wph + (size_t)c * HH + sl * 256;
        float s = 0.0f;
        #pragma unroll 4
        for (int kk = 0; kk < 64; ++kk) {           // 64 x 8B = 256 ushorts
            union { u64 u; ushort us[4]; } v;
            v.u = ld_agent(hrow + kk);              // bypass load: guaranteed fresh
            s += wrow[kk * 4 + 0] * b2f(v.us[0]);
            s += wrow[kk * 4 + 1] * b2f(v.us[1]);
            s += wrow[kk * 4 + 2] * b2f(v.us[2]);
            s += wrow[kk * 4 + 3] * b2f(v.us[3]);
        }
        part[tid] = s;
        __syncthreads();
        if (tid < 64) {
            float p = bp[c];
            #pragma unroll
            for (int w = 0; w < 8; ++w) p += part[w * 64 + c];
            float mx = p;
            #pragma unroll
            for (int off = 32; off > 0; off >>= 1) mx = fmaxf(mx, __shfl_xor(mx, off));
            float ex = expf(p - mx), sum = ex;
            #pragma unroll
            for (int off = 32; off > 0; off >>= 1) sum += __shfl_xor(sum, off);
            out[(size_t)b * CC + c] = p - mx - logf(sum);
        }
    }
}

// ---------------------------------------------------------------------------
extern "C" void kernel_launch(void* const* d_in, const int* in_sizes, int n_in,
                              void* d_out, int out_size, void* d_ws, size_t ws_size,
                              hipStream_t stream)
{
    const int*   x    = (const int*)  d_in[0];
    const float* emb  = (const float*)d_in[1];   // [64][1024]
    const float* Wgx  = (const float*)d_in[2];   // [2048][1024]
    const float* Wix  = (const float*)d_in[3];
    const float* Wfx  = (const float*)d_in[4];
    const float* Wox  = (const float*)d_in[5];
    const float* Wgh  = (const float*)d_in[6];   // [2048][2048]
    const float* Wih  = (const float*)d_in[7];
    const float* Wfh  = (const float*)d_in[8];
    const float* Woh  = (const float*)d_in[9];
    const float* bg   = (const float*)d_in[10];
    const float* bi   = (const float*)d_in[11];
    const float* bf_  = (const float*)d_in[12];
    const float* bo   = (const float*)d_in[13];
    const float* Wph  = (const float*)d_in[14];  // [64][2048]
    const float* bp   = (const float*)d_in[15];

    char* ws = (char*)d_ws;
    const size_t MB = 1048576;
    ushort*   Wp    = (ushort*)(ws);                    // 32 MB
    ushort*   Xhi   = (ushort*)(ws + 32 * MB);          // 16 MB
    ushort*   Xlo   = (ushort*)(ws + 48 * MB);          // 16 MB
    ushort*   Ehi   = (ushort*)(ws + 64 * MB);          // 128 KB
    ushort*   Elo   = (ushort*)(ws + 64 * MB + 131072); // 128 KB
    float*    xproj = (float*) (ws + 65 * MB);          //  2 MB
    ushort*   h0    = (ushort*)(ws + 67 * MB);          //  1 MB
    ushort*   h1    = (ushort*)(ws + 68 * MB);          //  1 MB
    unsigned* bar   = (unsigned*)(ws + 69 * MB);        //  4 B

    prep<<<24640, 256, 0, stream>>>(Wgh, Wih, Wfh, Woh, Wgx, Wix, Wfx, Wox, emb,
                                    Wp, Xhi, Xlo, Ehi, Elo);
    xz  <<<1152,  256, 0, stream>>>(Xhi, Xlo, Ehi, Elo, bg, bi, bf_, bo,
                                    xproj, (unsigned*)h0, bar);
    lstm_persist<<<256, 512, 0, stream>>>(Wp, xproj, x, h0, h1, bar,
                                          Wph, bp, (float*)d_out);
}